// Round 14
// baseline (290.485 us; speedup 1.0000x reference)
//
#include <hip/hip_runtime.h>
#include <stdint.h>

typedef unsigned short u16;
typedef __attribute__((ext_vector_type(8))) short short8;
typedef __attribute__((ext_vector_type(4))) float f32x4;
typedef __attribute__((ext_vector_type(2))) float f32x2;
typedef __attribute__((ext_vector_type(4))) unsigned int u32x4;

#define N_NODES 100000
#define RREL    3
#define NEDGE   1600000
#define NPAIR   1024
#define NSEG    (RREL * N_NODES)

// binned CSR build params
#define EPB   1024                         // smaller chunks: 4x more scatter blocks (latency tail fix)
#define NBLK  ((NEDGE + EPB - 1) / EPB)   // 1563
#define DPB   512                          // dsts per bin (dst >> 9)
#define NBIN  ((N_NODES + DPB - 1) / DPB)  // 196
#define LSEG  (DPB * RREL)                 // 1536 local segments per bin
#define CAP   12288                        // padded per-bin capacity
#define GSTR  16                           // gpos padding: 1 counter per 64B line

// prep kernel grid sections
#define PREP_TW   384                        // transpose: 384*256 = 98304 = 128*512+256*128
#define PREP_CAST (N_NODES * 128 / 8 / 256)  // 6250 cast blocks (2 x f32x4 per thread)

// ---------- bf16 helpers ----------
__device__ __forceinline__ float bflo(unsigned int u) {
    union { unsigned int u; float f; } c; c.u = u << 16; return c.f;
}
__device__ __forceinline__ float bfhi(unsigned int u) {
    union { unsigned int u; float f; } c; c.u = u & 0xffff0000u; return c.f;
}
__device__ __forceinline__ u16 f2bf(float f) {
    union { float f; unsigned int u; } c; c.f = f;
    unsigned int u = c.u;
    u += 0x7fffu + ((u >> 16) & 1u);   // round-to-nearest-even
    return (u16)(u >> 16);
}

// ---------- async global->LDS, 16B per lane ----------
__device__ __forceinline__ void async_copy16(const u16* g, u16* l) {
    __builtin_amdgcn_global_load_lds(
        (const __attribute__((address_space(1))) unsigned int*)g,
        (__attribute__((address_space(3))) unsigned int*)l,
        16, 0, 0);
}

// ========== merged prep: binscatter (count+reserve+scatter) | weight transpose | cast ==========
__global__ __launch_bounds__(256) void prep_kernel(const int* __restrict__ es,
                                                   const int* __restrict__ ed,
                                                   const int* __restrict__ et,
                                                   int* __restrict__ gpos,     // padded stride GSTR
                                                   unsigned int* __restrict__ binned,
                                                   const float* __restrict__ x,
                                                   u16* __restrict__ xb,
                                                   const float* __restrict__ Wrel1,
                                                   const float* __restrict__ Wroot1,
                                                   const float* __restrict__ Wrel2,
                                                   const float* __restrict__ Wroot2,
                                                   u16* __restrict__ Wt1,
                                                   u16* __restrict__ Wt2) {
    __shared__ int h[NBIN];
    __shared__ int base[NBIN];
    int b = blockIdx.x, t = threadIdx.x;
    if (b < NBLK) {
        // ---- binscatter: count, reserve (global atomic, padded counters), scatter ----
        for (int i = t; i < NBIN; i += 256) h[i] = 0;
        __syncthreads();
        int e0 = b * EPB;
        int e1 = e0 + EPB; if (e1 > NEDGE) e1 = NEDGE;
        for (int i = e0 + t; i < e1; i += 256)
            atomicAdd(&h[ed[i] >> 9], 1);
        __syncthreads();
        for (int i = t; i < NBIN; i += 256) {
            int c = h[i];
            base[i] = c ? atomicAdd(&gpos[i * GSTR], c) : 0;
            h[i] = 0;                       // reuse as running within-block offset
        }
        __syncthreads();
        for (int i = e0 + t; i < e1; i += 256) {
            int d = ed[i];
            int bin = d >> 9;
            unsigned int pk = ((unsigned int)es[i] << 11) | (unsigned int)((d & 511) * 3 + et[i]);
            int off = atomicAdd(&h[bin], 1);
            binned[(size_t)bin * CAP + base[bin] + off] = pk;
        }
    } else if (b < NBLK + PREP_TW) {
        // ---- weight transpose: Wt1 (128n x 512k), Wt2 (256n x 128k) ----
        int idx = (b - NBLK) * 256 + t;
        if (idx < 128 * 512) {
            int n = idx >> 9, k = idx & 511;
            float v = (k < 384) ? Wrel1[(size_t)k * 128 + n] : Wroot1[(size_t)(k - 384) * 128 + n];
            Wt1[idx] = f2bf(v);
        } else {
            int j = idx - 128 * 512;
            if (j < 256 * 128) {
                int n = j >> 7, k = j & 127;
                float v = (n < 192) ? Wrel2[((size_t)(n >> 6) * 128 + k) * 64 + (n & 63)]
                                    : Wroot2[(size_t)k * 64 + (n - 192)];
                Wt2[j] = f2bf(v);
            }
        }
    } else {
        // ---- cast x -> bf16, 8 elems/thread (2x f32x4, independent for ILP) ----
        int i0 = (b - NBLK - PREP_TW) * 512 + t;     // block covers 512 f32x4's
        f32x4 v0 = __builtin_nontemporal_load(&((const f32x4*)x)[i0]);
        f32x4 v1 = __builtin_nontemporal_load(&((const f32x4*)x)[i0 + 256]);
        uint2 o0, o1;
        o0.x = ((unsigned int)f2bf(v0.y) << 16) | (unsigned int)f2bf(v0.x);
        o0.y = ((unsigned int)f2bf(v0.w) << 16) | (unsigned int)f2bf(v0.z);
        o1.x = ((unsigned int)f2bf(v1.y) << 16) | (unsigned int)f2bf(v1.x);
        o1.y = ((unsigned int)f2bf(v1.w) << 16) | (unsigned int)f2bf(v1.z);
        ((uint2*)xb)[i0]       = o0;
        ((uint2*)xb)[i0 + 256] = o1;
    }
}

// ---------- p4: per-bin segment finalize + mark phase (bin owns its dsts' CSR) ----------
__global__ __launch_bounds__(256) void p4_finalize(const unsigned int* __restrict__ binned,
                                                   const int* __restrict__ gpos,
                                                   const int* __restrict__ nest,
                                                   const int* __restrict__ food,
                                                   int* __restrict__ seg_start,
                                                   int* __restrict__ cnt,
                                                   int* __restrict__ sorted_src,
                                                   int* __restrict__ flag) {
    __shared__ int h[LSEG];
    __shared__ int cur[LSEG];
    __shared__ int wtot4[4];
    int t = threadIdx.x, bin = blockIdx.x;
    for (int i = t; i < LSEG; i += 256) h[i] = 0;
    __syncthreads();
    int eb = bin * CAP;
    int ee = eb + gpos[bin * GSTR];
    for (int i = eb + t; i < ee; i += 256)
        atomicAdd(&h[binned[i] & 2047u], 1);
    __syncthreads();
    int i6 = t * 6;
    int s = 0;
    #pragma unroll
    for (int i = 0; i < 6; ++i) s += h[i6 + i];
    int lane = t & 63, wv = t >> 6;
    int incl = s;
    #pragma unroll
    for (int d = 1; d < 64; d <<= 1) { int v = __shfl_up(incl, d); if (lane >= d) incl += v; }
    if (lane == 63) wtot4[wv] = incl;
    __syncthreads();
    int wpre = 0;
    #pragma unroll
    for (int i = 0; i < 4; ++i) if (i < wv) wpre += wtot4[i];
    int run = wpre + incl - s;
    int segbase = bin * LSEG;
    #pragma unroll
    for (int i = 0; i < 6; ++i) {
        int ls = i6 + i;
        int c = h[ls];
        int seg = segbase + ls;
        if (seg < NSEG) { seg_start[seg] = eb + run; cnt[seg] = c; }
        cur[ls] = run;
        run += c;
    }
    __syncthreads();
    for (int i = eb + t; i < ee; i += 256) {
        unsigned int u = binned[i];
        int ls = (int)(u & 2047u);
        int p = atomicAdd(&cur[ls], 1);
        sorted_src[eb + p] = (int)(u >> 11);
    }
    __syncthreads();
    // ---- mark phase: flag referenced dsts in THIS bin + their edge srcs ----
    // (intra-block global RAW after barrier is same-CU coherent)
    for (int sl = t; sl < NPAIR * 2; sl += 256) {
        int p = sl >> 1, side = sl & 1;
        int dst = side ? food[p] : nest[p];
        if ((unsigned)dst >= (unsigned)N_NODES) dst = 0;
        if ((dst >> 9) == bin) {
            flag[dst] = 1;
            int ls0 = (dst & 511) * 3;
            int tot = h[ls0] + h[ls0 + 1] + h[ls0 + 2];   // h still holds per-seg counts
            int st0 = seg_start[dst * 3];
            for (int i = 0; i < tot; ++i)
                flag[sorted_src[st0 + i]] = 1;            // racing stores benign
        }
    }
}

// ---------- compact flagged nodes into list + inverse map ----------
__global__ __launch_bounds__(256) void compact_nodes(const int* __restrict__ flag,
                                                     int* __restrict__ ncnt,
                                                     int* __restrict__ list,
                                                     int* __restrict__ map) {
    int n = blockIdx.x * 256 + threadIdx.x;
    if (n >= N_NODES) return;
    if (flag[n]) {
        int idx = atomicAdd(ncnt, 1);
        list[idx] = n;
        map[n] = idx;
    }
}

// ========== fused layer-1 (compacted rows): BM=32, 512 threads ==========
__global__ __launch_bounds__(512, 8) void fused_l1(const uint4* __restrict__ X4,   // xb as (N,16) uint4
                                                   const u16* __restrict__ xb,     // same buffer, u16 view
                                                   const int* __restrict__ seg_start,
                                                   const int* __restrict__ cnt,
                                                   const int* __restrict__ sorted_src,
                                                   const u16* __restrict__ Wt1,
                                                   const float* __restrict__ b1,
                                                   const int* __restrict__ list,
                                                   const int* __restrict__ ncnt,
                                                   u16* __restrict__ h1c) {
    const int nc = *ncnt;
    const int bm  = blockIdx.x * 32;
    if (bm >= nc) return;                 // block-uniform early exit
    __shared__ __align__(16) u16 Aagg[32 * 392];   // 25088 B (row pad 392: ~2-way banks)
    __shared__ __align__(16) u16 Aroot[32 * 32];   //  2048 B
    __shared__ __align__(16) u16 Bs[128 * 32];     //  8192 B  => 35328 B total
    const int t = threadIdx.x;
    const int w = t >> 6, l = t & 63;
    const int q4 = l >> 4, ql = l & 15;
    const int qid = w * 4 + q4;            // quarter-wave id 0..31
    const int shbase = q4 * 16;

    // ---- phase A: gather 96 segment means into Aagg (32 quarter-waves, 3 passes) ----
    int cArr[3], stArr[3];
    #pragma unroll
    for (int sp = 0; sp < 3; ++sp) {
        int seg_local = sp * 32 + qid;
        int n_loc = seg_local / 3, rel = seg_local - n_loc * 3;
        int nid = list[bm + n_loc];        // tail entries are 0 (zero-init) -> harmless
        cArr[sp]  = cnt[nid * 3 + rel];
        stArr[sp] = seg_start[nid * 3 + rel];
    }
    #pragma unroll 1
    for (int sp = 0; sp < 3; ++sp) {
        int seg_local = sp * 32 + qid;
        int c  = cArr[sp];
        int st = stArr[sp];

        float a0 = 0.f, a1 = 0.f, a2 = 0.f, a3 = 0.f,
              a4 = 0.f, a5 = 0.f, a6 = 0.f, a7 = 0.f;

        for (int base = 0; base < c; base += 16) {
            int rem = c - base;                       // >= 1
            int ii  = (ql < rem) ? ql : (rem - 1);
            int idxv = sorted_src[st + base + ii];    // idx for edge base+ql (clamped)
            int lim = (rem < 16) ? rem : 16;
            for (int j = 0; j < lim; j += 4) {
                int e1 = j + 1, e2 = j + 2, e3 = j + 3;
                float w1 = (e1 < lim) ? 1.f : 0.f;
                float w2 = (e2 < lim) ? 1.f : 0.f;
                float w3 = (e3 < lim) ? 1.f : 0.f;
                int s0 = __shfl(idxv, shbase + j);
                int s1 = __shfl(idxv, shbase + ((e1 < lim) ? e1 : 0));
                int s2 = __shfl(idxv, shbase + ((e2 < lim) ? e2 : 0));
                int s3 = __shfl(idxv, shbase + ((e3 < lim) ? e3 : 0));
                uint4 v0 = X4[(size_t)s0 * 16 + ql];
                uint4 v1 = X4[(size_t)s1 * 16 + ql];
                uint4 v2 = X4[(size_t)s2 * 16 + ql];
                uint4 v3 = X4[(size_t)s3 * 16 + ql];
                a0 += bflo(v0.x);               a1 += bfhi(v0.x);
                a2 += bflo(v0.y);               a3 += bfhi(v0.y);
                a4 += bflo(v0.z);               a5 += bfhi(v0.z);
                a6 += bflo(v0.w);               a7 += bfhi(v0.w);
                a0 = fmaf(w1, bflo(v1.x), a0);  a1 = fmaf(w1, bfhi(v1.x), a1);
                a2 = fmaf(w1, bflo(v1.y), a2);  a3 = fmaf(w1, bfhi(v1.y), a3);
                a4 = fmaf(w1, bflo(v1.z), a4);  a5 = fmaf(w1, bfhi(v1.z), a5);
                a6 = fmaf(w1, bflo(v1.w), a6);  a7 = fmaf(w1, bfhi(v1.w), a7);
                a0 = fmaf(w2, bflo(v2.x), a0);  a1 = fmaf(w2, bfhi(v2.x), a1);
                a2 = fmaf(w2, bflo(v2.y), a2);  a3 = fmaf(w2, bfhi(v2.y), a3);
                a4 = fmaf(w2, bflo(v2.z), a4);  a5 = fmaf(w2, bfhi(v2.z), a5);
                a6 = fmaf(w2, bflo(v2.w), a6);  a7 = fmaf(w2, bfhi(v2.w), a7);
                a0 = fmaf(w3, bflo(v3.x), a0);  a1 = fmaf(w3, bfhi(v3.x), a1);
                a2 = fmaf(w3, bflo(v3.y), a2);  a3 = fmaf(w3, bfhi(v3.y), a3);
                a4 = fmaf(w3, bflo(v3.z), a4);  a5 = fmaf(w3, bfhi(v3.z), a5);
                a6 = fmaf(w3, bflo(v3.w), a6);  a7 = fmaf(w3, bfhi(v3.w), a7);
            }
        }
        float sc = 1.0f / (float)(c > 0 ? c : 1);
        u32x4 o;
        o.x = ((unsigned int)f2bf(a1 * sc) << 16) | (unsigned int)f2bf(a0 * sc);
        o.y = ((unsigned int)f2bf(a3 * sc) << 16) | (unsigned int)f2bf(a2 * sc);
        o.z = ((unsigned int)f2bf(a5 * sc) << 16) | (unsigned int)f2bf(a4 * sc);
        o.w = ((unsigned int)f2bf(a7 * sc) << 16) | (unsigned int)f2bf(a6 * sc);
        int n_loc = seg_local / 3;
        int rel   = seg_local - n_loc * 3;
        *(u32x4*)&Aagg[n_loc * 392 + rel * 128 + ql * 8] = o;
    }
    __syncthreads();   // Aagg complete

    // ---- phase B: GEMM 32x128, K=512 (k<384 from Aagg, k>=384 root staged from xb[list]) ----
    const int wm = w >> 2, wn = w & 3;     // 2x4 wave grid: WTM=16, WTN=32 (NI=2)
    const int q = l >> 4, lm = l & 15;
    f32x4 acc[2] = {};
    const int br  = t >> 2;            // 0..127 (Bs row; Aroot row for t<128)
    const int bc4 = (t & 3) * 8;       // 0,8,16,24

    for (int kt = 0; kt < 16; ++kt) {
        const int k0 = kt * 32;
        __syncthreads();   // previous iteration done reading Bs/Aroot
        async_copy16(Wt1 + (size_t)br * 512 + k0 + bc4, &Bs[br * 32 + bc4]);  // 1/thread, linear
        if (kt >= 12 && w < 2) {       // wave-uniform; t<128 -> br=0..31 covers 32 rows
            async_copy16(xb + (size_t)list[bm + br] * 128 + (k0 - 384) + bc4, &Aroot[br * 32 + bc4]);
        }
        __syncthreads();   // drains vmcnt before LDS reads
        short8 fa;
        if (kt < 12) fa = *(const short8*)&Aagg[(wm * 16 + lm) * 392 + k0 + q * 8];
        else         fa = *(const short8*)&Aroot[(wm * 16 + lm) * 32 + q * 8];
        #pragma unroll
        for (int ni = 0; ni < 2; ++ni) {
            short8 fb = *(const short8*)&Bs[(wn * 32 + ni * 16 + lm) * 32 + q * 8];
            acc[ni] = __builtin_amdgcn_mfma_f32_16x16x32_bf16(fa, fb, acc[ni], 0, 0, 0);
        }
    }
    // epilogue: C/D layout col=lane&15, row=q*4+reg; bias + relu -> bf16 h1c (compact row)
    #pragma unroll
    for (int ni = 0; ni < 2; ++ni) {
        int gc = wn * 32 + ni * 16 + lm;
        float bv = b1[gc];
        #pragma unroll
        for (int rg = 0; rg < 4; ++rg) {
            int gr = bm + wm * 16 + q * 4 + rg;      // compact row; tail rows harmless
            float v = fmaxf(acc[ni][rg] + bv, 0.0f);
            h1c[(size_t)gr * 128 + gc] = f2bf(v);
        }
    }
}

// ---------- layer-2 GEMM over compacted rows: Pc = h1c @ [Wrel2|..], nodec = h1c @ Wroot2 + b2 ----------
__global__ __launch_bounds__(256) void gemm2_c(const u16* __restrict__ h1c,
                                               const u16* __restrict__ Wt2,
                                               const float* __restrict__ b2,
                                               const int* __restrict__ ncnt,
                                               u16* __restrict__ Pc,      // (nc,192) bf16
                                               float* __restrict__ nodec) { // (nc,64) f32
    const int nc = *ncnt;
    const int bm = blockIdx.x * 64;
    if (bm >= nc) return;
    __shared__ __align__(16) u16 As[64 * 32];
    __shared__ __align__(16) u16 Bs[256 * 32];
    const int t = threadIdx.x;
    const int w = t >> 6, l = t & 63;
    const int wn = w;                      // WN=4, WM=1: WTM=64, WTN=64, MI=4, NI=4
    const int q = l >> 4, lm = l & 15;

    f32x4 acc[4][4] = {};
    const int ar = t >> 2;            // 0..63
    const int ac = (t & 3) * 8;       // 0,8,16,24

    int gr0 = bm + ar; if (gr0 >= nc) gr0 = nc - 1;

    for (int kt = 0; kt < 4; ++kt) {
        const int k0 = kt * 32;
        __syncthreads();
        async_copy16(h1c + (size_t)gr0 * 128 + k0 + ac, &As[ar * 32 + ac]);
        #pragma unroll
        for (int i = 0; i < 4; ++i)
            async_copy16(Wt2 + (size_t)(i * 64 + ar) * 128 + k0 + ac,
                         &Bs[(i * 64 + ar) * 32 + ac]);
        __syncthreads();
        short8 fa[4], fb[4];
        #pragma unroll
        for (int mi = 0; mi < 4; ++mi)
            fa[mi] = *(const short8*)&As[(mi * 16 + lm) * 32 + q * 8];
        #pragma unroll
        for (int ni = 0; ni < 4; ++ni)
            fb[ni] = *(const short8*)&Bs[(wn * 64 + ni * 16 + lm) * 32 + q * 8];
        #pragma unroll
        for (int mi = 0; mi < 4; ++mi)
            #pragma unroll
            for (int ni = 0; ni < 4; ++ni)
                acc[mi][ni] = __builtin_amdgcn_mfma_f32_16x16x32_bf16(
                    fa[mi], fb[ni], acc[mi][ni], 0, 0, 0);
    }
    #pragma unroll
    for (int mi = 0; mi < 4; ++mi) {
        #pragma unroll
        for (int ni = 0; ni < 4; ++ni) {
            int gc = wn * 64 + ni * 16 + lm;
            float bv = (gc >= 192) ? b2[gc - 192] : 0.0f;
            #pragma unroll
            for (int rg = 0; rg < 4; ++rg) {
                int gr = bm + mi * 16 + q * 4 + rg;
                if (gr < nc) {
                    float v = acc[mi][ni][rg] + bv;
                    if (gc < 192) Pc[(size_t)gr * 192 + gc] = f2bf(v);
                    else          nodec[(size_t)gr * 64 + (gc - 192)] = v;
                }
            }
        }
    }
}

// ---------- layer-2 aggregation for the 2048 (pair,side) slots, compact P/node via map ----------
__global__ __launch_bounds__(256) void seg_pair(const u16* __restrict__ Pc,      // (nc,192) bf16
                                                const int* __restrict__ seg_start,
                                                const int* __restrict__ cnt,
                                                const int* __restrict__ sorted_src,
                                                const float* __restrict__ nodec, // (nc,64) f32 root
                                                const int* __restrict__ map,
                                                const int* __restrict__ nest,
                                                const int* __restrict__ food,
                                                float* __restrict__ pairbuf) {   // (NPAIR,128) f32
    int lane = threadIdx.x & 63;
    int q4 = lane >> 4, ql = lane & 15;
    int e  = ql >> 3;            // edge slot 0/1
    int fl = ql & 7;             // feature chunk (8 feats = 16B)
    int slot = ((blockIdx.x * 256 + threadIdx.x) >> 6) * 4 + q4;   // 0..2047 (grid exact)
    int p = slot >> 1, side = slot & 1;
    int dst = side ? food[p] : nest[p];
    if ((unsigned)dst >= (unsigned)N_NODES) dst = 0;
    int shbase = q4 * 16;

    int c0 = cnt[dst * 3 + 0], c1 = cnt[dst * 3 + 1], c2 = cnt[dst * 3 + 2];
    int st = seg_start[dst * 3 + 0];        // rel segments contiguous
    int c01 = c0 + c1, tot = c01 + c2;
    float r0 = c0 ? 1.0f / (float)c0 : 0.0f;
    float r1 = c1 ? 1.0f / (float)c1 : 0.0f;
    float r2 = c2 ? 1.0f / (float)c2 : 0.0f;

    // root (f32) from gemm2_c (dst is flagged -> map valid)
    const f32x4* np = (const f32x4*)(nodec + (size_t)map[dst] * 64 + fl * 8);
    f32x4 z0 = *np;
    f32x4 z1 = *(np + 1);

    f32x2 d0 = {0.f,0.f}, d1 = {0.f,0.f}, d2 = {0.f,0.f}, d3 = {0.f,0.f};

    for (int base = 0; base < tot; base += 16) {
        int rem = tot - base;
        int ii  = (ql < rem) ? ql : 0;
        int idxv = sorted_src[st + base + ii];
        int lim = (rem < 16) ? rem : 16;

        uint4 v[8];
        #pragma unroll
        for (int k = 0; k < 8; ++k) {
            int jj = 2 * k + e;                 // batch-local edge for this slot
            int sel = (jj < lim) ? jj : 0;
            int s = __shfl(idxv, shbase + sel);
            int ge = base + sel;                // valid edge pos (clamped)
            int rel = (ge >= c0) + (ge >= c01);
            v[k] = *(const uint4*)(Pc + (size_t)map[s] * 192 + rel * 64 + fl * 8);
        }
        #pragma unroll
        for (int k = 0; k < 8; ++k) {
            int jj = 2 * k + e;
            int ge = base + jj;
            float wr = (jj < lim) ? ((ge < c0) ? r0 : ((ge < c01) ? r1 : r2)) : 0.0f;
            f32x2 wv = {wr, wr};
            d0 += wv * (f32x2){bflo(v[k].x), bfhi(v[k].x)};
            d1 += wv * (f32x2){bflo(v[k].y), bfhi(v[k].y)};
            d2 += wv * (f32x2){bflo(v[k].z), bfhi(v[k].z)};
            d3 += wv * (f32x2){bflo(v[k].w), bfhi(v[k].w)};
        }
    }
    // combine edge slots (lane l <-> l^8)
    d0.x += __shfl_xor(d0.x, 8); d0.y += __shfl_xor(d0.y, 8);
    d1.x += __shfl_xor(d1.x, 8); d1.y += __shfl_xor(d1.y, 8);
    d2.x += __shfl_xor(d2.x, 8); d2.y += __shfl_xor(d2.y, 8);
    d3.x += __shfl_xor(d3.x, 8); d3.y += __shfl_xor(d3.y, 8);
    if (e == 0) {
        f32x4 o0 = {z0.x + d0.x, z0.y + d0.y, z0.z + d1.x, z0.w + d1.y};
        f32x4 o1 = {z1.x + d2.x, z1.y + d2.y, z1.z + d3.x, z1.w + d3.y};
        f32x4* op = (f32x4*)(pairbuf + (size_t)p * 128 + side * 64 + fl * 8);
        *op       = o0;
        *(op + 1) = o1;
    }
}

// ---------- final pair MLP (reads pairbuf linearly) ----------
__global__ __launch_bounds__(128) void pair_mlp(const float* __restrict__ pairbuf,
                                                const float* __restrict__ fcW,
                                                const float* __restrict__ fcb,
                                                float* __restrict__ out) {
    int p = blockIdx.x;
    int t = threadIdx.x;
    __shared__ float pv[128];
    pv[t] = pairbuf[(size_t)p * 128 + t];
    __syncthreads();
    float s = fcb[t];
    #pragma unroll 4
    for (int k = 0; k < 128; ++k)
        s += pv[k] * fcW[k * 128 + t];
    out[(size_t)p * 128 + t] = tanhf(s);
}

extern "C" void kernel_launch(void* const* d_in, const int* in_sizes, int n_in,
                              void* d_out, int out_size, void* d_ws, size_t ws_size,
                              hipStream_t stream) {
    const float* x    = (const float*)d_in[0];
    const int* esrc   = (const int*)d_in[1];
    const int* edst   = (const int*)d_in[2];
    const int* etyp   = (const int*)d_in[3];
    const int* nest   = (const int*)d_in[5];
    const int* food   = (const int*)d_in[6];
    const float* Wrel1  = (const float*)d_in[7];
    const float* Wroot1 = (const float*)d_in[8];
    const float* b1     = (const float*)d_in[9];
    const float* Wrel2  = (const float*)d_in[10];
    const float* Wroot2 = (const float*)d_in[11];
    const float* b2     = (const float*)d_in[12];
    const float* fcW    = (const float*)d_in[13];
    const float* fcb    = (const float*)d_in[14];
    float* out = (float*)d_out;

    char* ws = (char*)d_ws;
    size_t off = 0;
    auto alloc_b = [&](size_t bytes) -> void* {
        void* p = ws + off;
        off += (bytes + 255) & ~(size_t)255;
        return p;
    };
    // zero-init block FIRST (single memset): gpos (padded) + ncnt + flag + list
    int* gpos        = (int*)alloc_b((size_t)NBIN * GSTR * 4);
    int* ncnt        = (int*)alloc_b(4);
    int* flag        = (int*)alloc_b((size_t)N_NODES * 4);
    int* list        = (int*)alloc_b((size_t)N_NODES * 4);
    size_t zspan     = (size_t)((char*)(list + N_NODES) - (char*)gpos);
    int* map         = (int*)alloc_b((size_t)N_NODES * 4);
    unsigned int* bn = (unsigned int*)alloc_b((size_t)NBIN * CAP * 4);
    int* seg_start   = (int*)alloc_b((size_t)NSEG * 4);
    int* cnt         = (int*)alloc_b((size_t)NSEG * 4);
    int* sorted_src  = (int*)alloc_b((size_t)NBIN * CAP * 4);
    u16* Wt1         = (u16*)alloc_b((size_t)128 * 512 * 2);
    u16* Wt2         = (u16*)alloc_b((size_t)256 * 128 * 2);
    u16* xb          = (u16*)alloc_b((size_t)N_NODES * 128 * 2);
    u16* Pc          = (u16*)alloc_b((size_t)N_NODES * 192 * 2);
    u16* h1c         = (u16*)alloc_b((size_t)N_NODES * 128 * 2);
    float* nodec     = (float*)alloc_b((size_t)N_NODES * 64 * 4);
    float* pairbuf   = (float*)alloc_b((size_t)NPAIR * 128 * 4);

    hipMemsetAsync(gpos, 0, zspan, stream);

    // merged prep: binscatter (1563 blocks) | weight transpose | x->bf16 cast (ILP x2)
    prep_kernel<<<NBLK + PREP_TW + PREP_CAST, 256, 0, stream>>>(
        esrc, edst, etyp, gpos, bn, x, xb, Wrel1, Wroot1, Wrel2, Wroot2, Wt1, Wt2);

    // per-bin segment finalize + mark (bin owns its dsts' CSR)
    p4_finalize<<<NBIN, 256, 0, stream>>>(bn, gpos, nest, food, seg_start, cnt, sorted_src, flag);

    // compact the ~30K flagged nodes
    compact_nodes<<<(N_NODES + 255) / 256, 256, 0, stream>>>(flag, ncnt, list, map);

    // layer 1 over compacted rows (BM=32 @ 512 threads)
    fused_l1<<<N_NODES / 32, 512, 0, stream>>>(
        (const uint4*)xb, xb, seg_start, cnt, sorted_src, Wt1, b1, list, ncnt, h1c);

    // layer 2 over compacted rows
    gemm2_c<<<(N_NODES + 63) / 64, 256, 0, stream>>>(h1c, Wt2, b2, ncnt, Pc, nodec);
    seg_pair<<<(NPAIR * 2) / 16, 256, 0, stream>>>(
        Pc, seg_start, cnt, sorted_src, nodec, map, nest, food, pairbuf);

    // pair MLP (f32, linear reads)
    pair_mlp<<<NPAIR, 128, 0, stream>>>(pairbuf, fcW, fcb, out);
}

// Round 16
// 271.162 us; speedup vs baseline: 1.0713x; 1.0713x over previous
//
#include <hip/hip_runtime.h>
#include <stdint.h>

typedef unsigned short u16;
typedef __attribute__((ext_vector_type(8))) short short8;
typedef __attribute__((ext_vector_type(4))) float f32x4;
typedef __attribute__((ext_vector_type(2))) float f32x2;
typedef __attribute__((ext_vector_type(4))) unsigned int u32x4;

#define N_NODES 100000
#define RREL    3
#define NEDGE   1600000
#define NPAIR   1024
#define NSEG    (RREL * N_NODES)

// binned CSR build params
#define EPB   4096                         // fat chunks: ~21-edge coalesced scatter runs, 76K atomics
#define NBLK  ((NEDGE + EPB - 1) / EPB)   // 391
#define DPB   512                          // dsts per bin (dst >> 9)
#define NBIN  ((N_NODES + DPB - 1) / DPB)  // 196
#define LSEG  (DPB * RREL)                 // 1536 local segments per bin
#define CAP   12288                        // padded per-bin capacity
#define GSTR  16                           // gpos padding: 1 counter per 64B line (atomic spread)

// prep kernel grid sections
#define PREP_TW   384                        // transpose: 384*256 = 98304 = 128*512+256*128
#define PREP_CAST (N_NODES * 128 / 8 / 256)  // 6250 cast blocks (2 x f32x4 per thread)

// ---------- bf16 helpers ----------
__device__ __forceinline__ float bflo(unsigned int u) {
    union { unsigned int u; float f; } c; c.u = u << 16; return c.f;
}
__device__ __forceinline__ float bfhi(unsigned int u) {
    union { unsigned int u; float f; } c; c.u = u & 0xffff0000u; return c.f;
}
__device__ __forceinline__ u16 f2bf(float f) {
    union { float f; unsigned int u; } c; c.f = f;
    unsigned int u = c.u;
    u += 0x7fffu + ((u >> 16) & 1u);   // round-to-nearest-even
    return (u16)(u >> 16);
}

// ---------- async global->LDS, 16B per lane ----------
__device__ __forceinline__ void async_copy16(const u16* g, u16* l) {
    __builtin_amdgcn_global_load_lds(
        (const __attribute__((address_space(1))) unsigned int*)g,
        (__attribute__((address_space(3))) unsigned int*)l,
        16, 0, 0);
}

// ========== merged prep: binscatter (count+reserve+scatter) | weight transpose | cast ==========
__global__ __launch_bounds__(256) void prep_kernel(const int* __restrict__ es,
                                                   const int* __restrict__ ed,
                                                   const int* __restrict__ et,
                                                   int* __restrict__ gpos,     // padded stride GSTR
                                                   unsigned int* __restrict__ binned,
                                                   const float* __restrict__ x,
                                                   u16* __restrict__ xb,
                                                   const float* __restrict__ Wrel1,
                                                   const float* __restrict__ Wroot1,
                                                   const float* __restrict__ Wrel2,
                                                   const float* __restrict__ Wroot2,
                                                   u16* __restrict__ Wt1,
                                                   u16* __restrict__ Wt2) {
    __shared__ int h[NBIN];
    __shared__ int base[NBIN];
    int b = blockIdx.x, t = threadIdx.x;
    if (b < NBLK) {
        // ---- binscatter: count, reserve (global atomic, padded counters), scatter ----
        for (int i = t; i < NBIN; i += 256) h[i] = 0;
        __syncthreads();
        int e0 = b * EPB;
        int e1 = e0 + EPB; if (e1 > NEDGE) e1 = NEDGE;
        for (int i = e0 + t; i < e1; i += 256)
            atomicAdd(&h[ed[i] >> 9], 1);
        __syncthreads();
        for (int i = t; i < NBIN; i += 256) {
            int c = h[i];
            base[i] = c ? atomicAdd(&gpos[i * GSTR], c) : 0;
            h[i] = 0;                       // reuse as running within-block offset
        }
        __syncthreads();
        for (int i = e0 + t; i < e1; i += 256) {
            int d = ed[i];
            int bin = d >> 9;
            unsigned int pk = ((unsigned int)es[i] << 11) | (unsigned int)((d & 511) * 3 + et[i]);
            int off = atomicAdd(&h[bin], 1);
            binned[(size_t)bin * CAP + base[bin] + off] = pk;
        }
    } else if (b < NBLK + PREP_TW) {
        // ---- weight transpose: Wt1 (128n x 512k), Wt2 (256n x 128k) ----
        int idx = (b - NBLK) * 256 + t;
        if (idx < 128 * 512) {
            int n = idx >> 9, k = idx & 511;
            float v = (k < 384) ? Wrel1[(size_t)k * 128 + n] : Wroot1[(size_t)(k - 384) * 128 + n];
            Wt1[idx] = f2bf(v);
        } else {
            int j = idx - 128 * 512;
            if (j < 256 * 128) {
                int n = j >> 7, k = j & 127;
                float v = (n < 192) ? Wrel2[((size_t)(n >> 6) * 128 + k) * 64 + (n & 63)]
                                    : Wroot2[(size_t)k * 64 + (n - 192)];
                Wt2[j] = f2bf(v);
            }
        }
    } else {
        // ---- cast x -> bf16, 8 elems/thread (2x f32x4, independent for ILP) ----
        int i0 = (b - NBLK - PREP_TW) * 512 + t;     // block covers 512 f32x4's
        f32x4 v0 = __builtin_nontemporal_load(&((const f32x4*)x)[i0]);
        f32x4 v1 = __builtin_nontemporal_load(&((const f32x4*)x)[i0 + 256]);
        uint2 o0, o1;
        o0.x = ((unsigned int)f2bf(v0.y) << 16) | (unsigned int)f2bf(v0.x);
        o0.y = ((unsigned int)f2bf(v0.w) << 16) | (unsigned int)f2bf(v0.z);
        o1.x = ((unsigned int)f2bf(v1.y) << 16) | (unsigned int)f2bf(v1.x);
        o1.y = ((unsigned int)f2bf(v1.w) << 16) | (unsigned int)f2bf(v1.z);
        ((uint2*)xb)[i0]       = o0;
        ((uint2*)xb)[i0 + 256] = o1;
    }
}

// ---------- p4: per-bin segment finalize + mark phase (bin owns its dsts' CSR) ----------
__global__ __launch_bounds__(256) void p4_finalize(const unsigned int* __restrict__ binned,
                                                   const int* __restrict__ gpos,
                                                   const int* __restrict__ nest,
                                                   const int* __restrict__ food,
                                                   int* __restrict__ seg_start,
                                                   int* __restrict__ cnt,
                                                   int* __restrict__ sorted_src,
                                                   int* __restrict__ flag) {
    __shared__ int h[LSEG];
    __shared__ int cur[LSEG];
    __shared__ int wtot4[4];
    int t = threadIdx.x, bin = blockIdx.x;
    for (int i = t; i < LSEG; i += 256) h[i] = 0;
    __syncthreads();
    int eb = bin * CAP;
    int ee = eb + gpos[bin * GSTR];
    for (int i = eb + t; i < ee; i += 256)
        atomicAdd(&h[binned[i] & 2047u], 1);
    __syncthreads();
    int i6 = t * 6;
    int s = 0;
    #pragma unroll
    for (int i = 0; i < 6; ++i) s += h[i6 + i];
    int lane = t & 63, wv = t >> 6;
    int incl = s;
    #pragma unroll
    for (int d = 1; d < 64; d <<= 1) { int v = __shfl_up(incl, d); if (lane >= d) incl += v; }
    if (lane == 63) wtot4[wv] = incl;
    __syncthreads();
    int wpre = 0;
    #pragma unroll
    for (int i = 0; i < 4; ++i) if (i < wv) wpre += wtot4[i];
    int run = wpre + incl - s;
    int segbase = bin * LSEG;
    #pragma unroll
    for (int i = 0; i < 6; ++i) {
        int ls = i6 + i;
        int c = h[ls];
        int seg = segbase + ls;
        if (seg < NSEG) { seg_start[seg] = eb + run; cnt[seg] = c; }
        cur[ls] = run;
        run += c;
    }
    __syncthreads();
    for (int i = eb + t; i < ee; i += 256) {
        unsigned int u = binned[i];
        int ls = (int)(u & 2047u);
        int p = atomicAdd(&cur[ls], 1);
        sorted_src[eb + p] = (int)(u >> 11);
    }
    __syncthreads();
    // ---- mark phase: flag referenced dsts in THIS bin + their edge srcs ----
    // (intra-block global RAW after barrier is same-CU coherent)
    for (int sl = t; sl < NPAIR * 2; sl += 256) {
        int p = sl >> 1, side = sl & 1;
        int dst = side ? food[p] : nest[p];
        if ((unsigned)dst >= (unsigned)N_NODES) dst = 0;
        if ((dst >> 9) == bin) {
            flag[dst] = 1;
            int ls0 = (dst & 511) * 3;
            int tot = h[ls0] + h[ls0 + 1] + h[ls0 + 2];   // h still holds per-seg counts
            int st0 = seg_start[dst * 3];
            for (int i = 0; i < tot; ++i)
                flag[sorted_src[st0 + i]] = 1;            // racing stores benign
        }
    }
}

// ---------- compact flagged nodes into list + inverse map ----------
__global__ __launch_bounds__(256) void compact_nodes(const int* __restrict__ flag,
                                                     int* __restrict__ ncnt,
                                                     int* __restrict__ list,
                                                     int* __restrict__ map) {
    int n = blockIdx.x * 256 + threadIdx.x;
    if (n >= N_NODES) return;
    if (flag[n]) {
        int idx = atomicAdd(ncnt, 1);
        list[idx] = n;
        map[n] = idx;
    }
}

// ========== fused layer-1 (compacted rows): BM=32, 512 threads ==========
__global__ __launch_bounds__(512, 8) void fused_l1(const uint4* __restrict__ X4,   // xb as (N,16) uint4
                                                   const u16* __restrict__ xb,     // same buffer, u16 view
                                                   const int* __restrict__ seg_start,
                                                   const int* __restrict__ cnt,
                                                   const int* __restrict__ sorted_src,
                                                   const u16* __restrict__ Wt1,
                                                   const float* __restrict__ b1,
                                                   const int* __restrict__ list,
                                                   const int* __restrict__ ncnt,
                                                   u16* __restrict__ h1c) {
    const int nc = *ncnt;
    const int bm  = blockIdx.x * 32;
    if (bm >= nc) return;                 // block-uniform early exit
    __shared__ __align__(16) u16 Aagg[32 * 392];   // 25088 B (row pad 392: ~2-way banks)
    __shared__ __align__(16) u16 Aroot[32 * 32];   //  2048 B
    __shared__ __align__(16) u16 Bs[128 * 32];     //  8192 B  => 35328 B total
    const int t = threadIdx.x;
    const int w = t >> 6, l = t & 63;
    const int q4 = l >> 4, ql = l & 15;
    const int qid = w * 4 + q4;            // quarter-wave id 0..31
    const int shbase = q4 * 16;

    // ---- phase A: gather 96 segment means into Aagg (32 quarter-waves, 3 passes) ----
    int cArr[3], stArr[3];
    #pragma unroll
    for (int sp = 0; sp < 3; ++sp) {
        int seg_local = sp * 32 + qid;
        int n_loc = seg_local / 3, rel = seg_local - n_loc * 3;
        int nid = list[bm + n_loc];        // tail entries are 0 (zero-init) -> harmless
        cArr[sp]  = cnt[nid * 3 + rel];
        stArr[sp] = seg_start[nid * 3 + rel];
    }
    #pragma unroll 1
    for (int sp = 0; sp < 3; ++sp) {
        int seg_local = sp * 32 + qid;
        int c  = cArr[sp];
        int st = stArr[sp];

        float a0 = 0.f, a1 = 0.f, a2 = 0.f, a3 = 0.f,
              a4 = 0.f, a5 = 0.f, a6 = 0.f, a7 = 0.f;

        for (int base = 0; base < c; base += 16) {
            int rem = c - base;                       // >= 1
            int ii  = (ql < rem) ? ql : (rem - 1);
            int idxv = sorted_src[st + base + ii];    // idx for edge base+ql (clamped)
            int lim = (rem < 16) ? rem : 16;
            for (int j = 0; j < lim; j += 4) {
                int e1 = j + 1, e2 = j + 2, e3 = j + 3;
                float w1 = (e1 < lim) ? 1.f : 0.f;
                float w2 = (e2 < lim) ? 1.f : 0.f;
                float w3 = (e3 < lim) ? 1.f : 0.f;
                int s0 = __shfl(idxv, shbase + j);
                int s1 = __shfl(idxv, shbase + ((e1 < lim) ? e1 : 0));
                int s2 = __shfl(idxv, shbase + ((e2 < lim) ? e2 : 0));
                int s3 = __shfl(idxv, shbase + ((e3 < lim) ? e3 : 0));
                uint4 v0 = X4[(size_t)s0 * 16 + ql];
                uint4 v1 = X4[(size_t)s1 * 16 + ql];
                uint4 v2 = X4[(size_t)s2 * 16 + ql];
                uint4 v3 = X4[(size_t)s3 * 16 + ql];
                a0 += bflo(v0.x);               a1 += bfhi(v0.x);
                a2 += bflo(v0.y);               a3 += bfhi(v0.y);
                a4 += bflo(v0.z);               a5 += bfhi(v0.z);
                a6 += bflo(v0.w);               a7 += bfhi(v0.w);
                a0 = fmaf(w1, bflo(v1.x), a0);  a1 = fmaf(w1, bfhi(v1.x), a1);
                a2 = fmaf(w1, bflo(v1.y), a2);  a3 = fmaf(w1, bfhi(v1.y), a3);
                a4 = fmaf(w1, bflo(v1.z), a4);  a5 = fmaf(w1, bfhi(v1.z), a5);
                a6 = fmaf(w1, bflo(v1.w), a6);  a7 = fmaf(w1, bfhi(v1.w), a7);
                a0 = fmaf(w2, bflo(v2.x), a0);  a1 = fmaf(w2, bfhi(v2.x), a1);
                a2 = fmaf(w2, bflo(v2.y), a2);  a3 = fmaf(w2, bfhi(v2.y), a3);
                a4 = fmaf(w2, bflo(v2.z), a4);  a5 = fmaf(w2, bfhi(v2.z), a5);
                a6 = fmaf(w2, bflo(v2.w), a6);  a7 = fmaf(w2, bfhi(v2.w), a7);
                a0 = fmaf(w3, bflo(v3.x), a0);  a1 = fmaf(w3, bfhi(v3.x), a1);
                a2 = fmaf(w3, bflo(v3.y), a2);  a3 = fmaf(w3, bfhi(v3.y), a3);
                a4 = fmaf(w3, bflo(v3.z), a4);  a5 = fmaf(w3, bfhi(v3.z), a5);
                a6 = fmaf(w3, bflo(v3.w), a6);  a7 = fmaf(w3, bfhi(v3.w), a7);
            }
        }
        float sc = 1.0f / (float)(c > 0 ? c : 1);
        u32x4 o;
        o.x = ((unsigned int)f2bf(a1 * sc) << 16) | (unsigned int)f2bf(a0 * sc);
        o.y = ((unsigned int)f2bf(a3 * sc) << 16) | (unsigned int)f2bf(a2 * sc);
        o.z = ((unsigned int)f2bf(a5 * sc) << 16) | (unsigned int)f2bf(a4 * sc);
        o.w = ((unsigned int)f2bf(a7 * sc) << 16) | (unsigned int)f2bf(a6 * sc);
        int n_loc = seg_local / 3;
        int rel   = seg_local - n_loc * 3;
        *(u32x4*)&Aagg[n_loc * 392 + rel * 128 + ql * 8] = o;
    }
    __syncthreads();   // Aagg complete

    // ---- phase B: GEMM 32x128, K=512 (k<384 from Aagg, k>=384 root staged from xb[list]) ----
    const int wm = w >> 2, wn = w & 3;     // 2x4 wave grid: WTM=16, WTN=32 (NI=2)
    const int q = l >> 4, lm = l & 15;
    f32x4 acc[2] = {};
    const int br  = t >> 2;            // 0..127 (Bs row; Aroot row for t<128)
    const int bc4 = (t & 3) * 8;       // 0,8,16,24

    for (int kt = 0; kt < 16; ++kt) {
        const int k0 = kt * 32;
        __syncthreads();   // previous iteration done reading Bs/Aroot
        async_copy16(Wt1 + (size_t)br * 512 + k0 + bc4, &Bs[br * 32 + bc4]);  // 1/thread, linear
        if (kt >= 12 && w < 2) {       // wave-uniform; t<128 -> br=0..31 covers 32 rows
            async_copy16(xb + (size_t)list[bm + br] * 128 + (k0 - 384) + bc4, &Aroot[br * 32 + bc4]);
        }
        __syncthreads();   // drains vmcnt before LDS reads
        short8 fa;
        if (kt < 12) fa = *(const short8*)&Aagg[(wm * 16 + lm) * 392 + k0 + q * 8];
        else         fa = *(const short8*)&Aroot[(wm * 16 + lm) * 32 + q * 8];
        #pragma unroll
        for (int ni = 0; ni < 2; ++ni) {
            short8 fb = *(const short8*)&Bs[(wn * 32 + ni * 16 + lm) * 32 + q * 8];
            acc[ni] = __builtin_amdgcn_mfma_f32_16x16x32_bf16(fa, fb, acc[ni], 0, 0, 0);
        }
    }
    // epilogue: C/D layout col=lane&15, row=q*4+reg; bias + relu -> bf16 h1c (compact row)
    #pragma unroll
    for (int ni = 0; ni < 2; ++ni) {
        int gc = wn * 32 + ni * 16 + lm;
        float bv = b1[gc];
        #pragma unroll
        for (int rg = 0; rg < 4; ++rg) {
            int gr = bm + wm * 16 + q * 4 + rg;      // compact row; tail rows harmless
            float v = fmaxf(acc[ni][rg] + bv, 0.0f);
            h1c[(size_t)gr * 128 + gc] = f2bf(v);
        }
    }
}

// ---------- layer-2 GEMM over compacted rows: Pc = h1c @ [Wrel2|..], nodec = h1c @ Wroot2 + b2 ----------
__global__ __launch_bounds__(256) void gemm2_c(const u16* __restrict__ h1c,
                                               const u16* __restrict__ Wt2,
                                               const float* __restrict__ b2,
                                               const int* __restrict__ ncnt,
                                               u16* __restrict__ Pc,      // (nc,192) bf16
                                               float* __restrict__ nodec) { // (nc,64) f32
    const int nc = *ncnt;
    const int bm = blockIdx.x * 64;
    if (bm >= nc) return;
    __shared__ __align__(16) u16 As[64 * 32];
    __shared__ __align__(16) u16 Bs[256 * 32];
    const int t = threadIdx.x;
    const int w = t >> 6, l = t & 63;
    const int wn = w;                      // WN=4, WM=1: WTM=64, WTN=64, MI=4, NI=4
    const int q = l >> 4, lm = l & 15;

    f32x4 acc[4][4] = {};
    const int ar = t >> 2;            // 0..63
    const int ac = (t & 3) * 8;       // 0,8,16,24

    int gr0 = bm + ar; if (gr0 >= nc) gr0 = nc - 1;

    for (int kt = 0; kt < 4; ++kt) {
        const int k0 = kt * 32;
        __syncthreads();
        async_copy16(h1c + (size_t)gr0 * 128 + k0 + ac, &As[ar * 32 + ac]);
        #pragma unroll
        for (int i = 0; i < 4; ++i)
            async_copy16(Wt2 + (size_t)(i * 64 + ar) * 128 + k0 + ac,
                         &Bs[(i * 64 + ar) * 32 + ac]);
        __syncthreads();
        short8 fa[4], fb[4];
        #pragma unroll
        for (int mi = 0; mi < 4; ++mi)
            fa[mi] = *(const short8*)&As[(mi * 16 + lm) * 32 + q * 8];
        #pragma unroll
        for (int ni = 0; ni < 4; ++ni)
            fb[ni] = *(const short8*)&Bs[(wn * 64 + ni * 16 + lm) * 32 + q * 8];
        #pragma unroll
        for (int mi = 0; mi < 4; ++mi)
            #pragma unroll
            for (int ni = 0; ni < 4; ++ni)
                acc[mi][ni] = __builtin_amdgcn_mfma_f32_16x16x32_bf16(
                    fa[mi], fb[ni], acc[mi][ni], 0, 0, 0);
    }
    #pragma unroll
    for (int mi = 0; mi < 4; ++mi) {
        #pragma unroll
        for (int ni = 0; ni < 4; ++ni) {
            int gc = wn * 64 + ni * 16 + lm;
            float bv = (gc >= 192) ? b2[gc - 192] : 0.0f;
            #pragma unroll
            for (int rg = 0; rg < 4; ++rg) {
                int gr = bm + mi * 16 + q * 4 + rg;
                if (gr < nc) {
                    float v = acc[mi][ni][rg] + bv;
                    if (gc < 192) Pc[(size_t)gr * 192 + gc] = f2bf(v);
                    else          nodec[(size_t)gr * 64 + (gc - 192)] = v;
                }
            }
        }
    }
}

// ---------- layer-2 aggregation for the 2048 (pair,side) slots, compact P/node via map ----------
__global__ __launch_bounds__(256) void seg_pair(const u16* __restrict__ Pc,      // (nc,192) bf16
                                                const int* __restrict__ seg_start,
                                                const int* __restrict__ cnt,
                                                const int* __restrict__ sorted_src,
                                                const float* __restrict__ nodec, // (nc,64) f32 root
                                                const int* __restrict__ map,
                                                const int* __restrict__ nest,
                                                const int* __restrict__ food,
                                                float* __restrict__ pairbuf) {   // (NPAIR,128) f32
    int lane = threadIdx.x & 63;
    int q4 = lane >> 4, ql = lane & 15;
    int e  = ql >> 3;            // edge slot 0/1
    int fl = ql & 7;             // feature chunk (8 feats = 16B)
    int slot = ((blockIdx.x * 256 + threadIdx.x) >> 6) * 4 + q4;   // 0..2047 (grid exact)
    int p = slot >> 1, side = slot & 1;
    int dst = side ? food[p] : nest[p];
    if ((unsigned)dst >= (unsigned)N_NODES) dst = 0;
    int shbase = q4 * 16;

    int c0 = cnt[dst * 3 + 0], c1 = cnt[dst * 3 + 1], c2 = cnt[dst * 3 + 2];
    int st = seg_start[dst * 3 + 0];        // rel segments contiguous
    int c01 = c0 + c1, tot = c01 + c2;
    float r0 = c0 ? 1.0f / (float)c0 : 0.0f;
    float r1 = c1 ? 1.0f / (float)c1 : 0.0f;
    float r2 = c2 ? 1.0f / (float)c2 : 0.0f;

    // root (f32) from gemm2_c (dst is flagged -> map valid)
    const f32x4* np = (const f32x4*)(nodec + (size_t)map[dst] * 64 + fl * 8);
    f32x4 z0 = *np;
    f32x4 z1 = *(np + 1);

    f32x2 d0 = {0.f,0.f}, d1 = {0.f,0.f}, d2 = {0.f,0.f}, d3 = {0.f,0.f};

    for (int base = 0; base < tot; base += 16) {
        int rem = tot - base;
        int ii  = (ql < rem) ? ql : 0;
        int idxv = sorted_src[st + base + ii];
        int lim = (rem < 16) ? rem : 16;

        uint4 v[8];
        #pragma unroll
        for (int k = 0; k < 8; ++k) {
            int jj = 2 * k + e;                 // batch-local edge for this slot
            int sel = (jj < lim) ? jj : 0;
            int s = __shfl(idxv, shbase + sel);
            int ge = base + sel;                // valid edge pos (clamped)
            int rel = (ge >= c0) + (ge >= c01);
            v[k] = *(const uint4*)(Pc + (size_t)map[s] * 192 + rel * 64 + fl * 8);
        }
        #pragma unroll
        for (int k = 0; k < 8; ++k) {
            int jj = 2 * k + e;
            int ge = base + jj;
            float wr = (jj < lim) ? ((ge < c0) ? r0 : ((ge < c01) ? r1 : r2)) : 0.0f;
            f32x2 wv = {wr, wr};
            d0 += wv * (f32x2){bflo(v[k].x), bfhi(v[k].x)};
            d1 += wv * (f32x2){bflo(v[k].y), bfhi(v[k].y)};
            d2 += wv * (f32x2){bflo(v[k].z), bfhi(v[k].z)};
            d3 += wv * (f32x2){bflo(v[k].w), bfhi(v[k].w)};
        }
    }
    // combine edge slots (lane l <-> l^8)
    d0.x += __shfl_xor(d0.x, 8); d0.y += __shfl_xor(d0.y, 8);
    d1.x += __shfl_xor(d1.x, 8); d1.y += __shfl_xor(d1.y, 8);
    d2.x += __shfl_xor(d2.x, 8); d2.y += __shfl_xor(d2.y, 8);
    d3.x += __shfl_xor(d3.x, 8); d3.y += __shfl_xor(d3.y, 8);
    if (e == 0) {
        f32x4 o0 = {z0.x + d0.x, z0.y + d0.y, z0.z + d1.x, z0.w + d1.y};
        f32x4 o1 = {z1.x + d2.x, z1.y + d2.y, z1.z + d3.x, z1.w + d3.y};
        f32x4* op = (f32x4*)(pairbuf + (size_t)p * 128 + side * 64 + fl * 8);
        *op       = o0;
        *(op + 1) = o1;
    }
}

// ---------- final pair MLP (reads pairbuf linearly) ----------
__global__ __launch_bounds__(128) void pair_mlp(const float* __restrict__ pairbuf,
                                                const float* __restrict__ fcW,
                                                const float* __restrict__ fcb,
                                                float* __restrict__ out) {
    int p = blockIdx.x;
    int t = threadIdx.x;
    __shared__ float pv[128];
    pv[t] = pairbuf[(size_t)p * 128 + t];
    __syncthreads();
    float s = fcb[t];
    #pragma unroll 4
    for (int k = 0; k < 128; ++k)
        s += pv[k] * fcW[k * 128 + t];
    out[(size_t)p * 128 + t] = tanhf(s);
}

extern "C" void kernel_launch(void* const* d_in, const int* in_sizes, int n_in,
                              void* d_out, int out_size, void* d_ws, size_t ws_size,
                              hipStream_t stream) {
    const float* x    = (const float*)d_in[0];
    const int* esrc   = (const int*)d_in[1];
    const int* edst   = (const int*)d_in[2];
    const int* etyp   = (const int*)d_in[3];
    const int* nest   = (const int*)d_in[5];
    const int* food   = (const int*)d_in[6];
    const float* Wrel1  = (const float*)d_in[7];
    const float* Wroot1 = (const float*)d_in[8];
    const float* b1     = (const float*)d_in[9];
    const float* Wrel2  = (const float*)d_in[10];
    const float* Wroot2 = (const float*)d_in[11];
    const float* b2     = (const float*)d_in[12];
    const float* fcW    = (const float*)d_in[13];
    const float* fcb    = (const float*)d_in[14];
    float* out = (float*)d_out;

    char* ws = (char*)d_ws;
    size_t off = 0;
    auto alloc_b = [&](size_t bytes) -> void* {
        void* p = ws + off;
        off += (bytes + 255) & ~(size_t)255;
        return p;
    };
    // zero-init block FIRST (single memset): gpos (padded) + ncnt + flag + list
    int* gpos        = (int*)alloc_b((size_t)NBIN * GSTR * 4);
    int* ncnt        = (int*)alloc_b(4);
    int* flag        = (int*)alloc_b((size_t)N_NODES * 4);
    int* list        = (int*)alloc_b((size_t)N_NODES * 4);
    size_t zspan     = (size_t)((char*)(list + N_NODES) - (char*)gpos);
    int* map         = (int*)alloc_b((size_t)N_NODES * 4);
    unsigned int* bn = (unsigned int*)alloc_b((size_t)NBIN * CAP * 4);
    int* seg_start   = (int*)alloc_b((size_t)NSEG * 4);
    int* cnt         = (int*)alloc_b((size_t)NSEG * 4);
    int* sorted_src  = (int*)alloc_b((size_t)NBIN * CAP * 4);
    u16* Wt1         = (u16*)alloc_b((size_t)128 * 512 * 2);
    u16* Wt2         = (u16*)alloc_b((size_t)256 * 128 * 2);
    u16* xb          = (u16*)alloc_b((size_t)N_NODES * 128 * 2);
    u16* Pc          = (u16*)alloc_b((size_t)N_NODES * 192 * 2);
    u16* h1c         = (u16*)alloc_b((size_t)N_NODES * 128 * 2);
    float* nodec     = (float*)alloc_b((size_t)N_NODES * 64 * 4);
    float* pairbuf   = (float*)alloc_b((size_t)NPAIR * 128 * 4);

    hipMemsetAsync(gpos, 0, zspan, stream);

    // merged prep: binscatter (391 fat blocks, padded counters) | weight transpose | cast
    prep_kernel<<<NBLK + PREP_TW + PREP_CAST, 256, 0, stream>>>(
        esrc, edst, etyp, gpos, bn, x, xb, Wrel1, Wroot1, Wrel2, Wroot2, Wt1, Wt2);

    // per-bin segment finalize + mark (bin owns its dsts' CSR)
    p4_finalize<<<NBIN, 256, 0, stream>>>(bn, gpos, nest, food, seg_start, cnt, sorted_src, flag);

    // compact the ~30K flagged nodes
    compact_nodes<<<(N_NODES + 255) / 256, 256, 0, stream>>>(flag, ncnt, list, map);

    // layer 1 over compacted rows (BM=32 @ 512 threads)
    fused_l1<<<N_NODES / 32, 512, 0, stream>>>(
        (const uint4*)xb, xb, seg_start, cnt, sorted_src, Wt1, b1, list, ncnt, h1c);

    // layer 2 over compacted rows
    gemm2_c<<<(N_NODES + 63) / 64, 256, 0, stream>>>(h1c, Wt2, b2, ncnt, Pc, nodec);
    seg_pair<<<(NPAIR * 2) / 16, 256, 0, stream>>>(
        Pc, seg_start, cnt, sorted_src, nodec, map, nest, food, pairbuf);

    // pair MLP (f32, linear reads)
    pair_mlp<<<NPAIR, 128, 0, stream>>>(pairbuf, fcW, fcb, out);
}